// Round 2
// baseline (825.148 us; speedup 1.0000x reference)
//
#include <hip/hip_runtime.h>
#include <hip/hip_bf16.h>

#define B_  32
#define S_  4096
#define D_  512
#define DA_ 256
#define R_  8

// ---------------------------------------------------------------------------
// k1: scores[b,r,s] = sum_a Ws2[r,a] * tanh( sum_d x[b,s,d] * Ws1[a,d] )
// GEMM M=B*S, N=DA=256, K=D=512. Tile 128 rows x 256 cols, block 256 (16x16),
// micro-tile 8x16 per thread. LDS: xs[128][36] (+XOR k4 swizzle), wsm[256][36].
// fp32 on VALU (no fp32-input MFMA on CDNA4). Expected VALU-bound.
// ---------------------------------------------------------------------------
__global__ __launch_bounds__(256, 2) void k1_scores(
    const float* __restrict__ x, const float* __restrict__ Ws1,
    const float* __restrict__ Ws2, float* __restrict__ scores)
{
    __shared__ float xs[128 * 36];   // 18432 B
    __shared__ float wsm[256 * 36];  // 36864 B
    const int tid = threadIdx.x;
    const int tx = tid & 15, ty = tid >> 4;
    const int b  = blockIdx.x >> 5;          // 32 s-tiles per batch
    const int s0 = (blockIdx.x & 31) << 7;   // tile start in s
    const float* xbase = x + ((size_t)b * S_ + s0) * D_;

    float acc[8][16];
    #pragma unroll
    for (int i = 0; i < 8; ++i)
        #pragma unroll
        for (int j = 0; j < 16; ++j) acc[i][j] = 0.f;

    const int lr  = tid >> 3;   // 0..31
    const int lk4 = tid & 7;    // 0..7
    const int lk  = lk4 << 2;

    for (int k0 = 0; k0 < D_; k0 += 32) {
        __syncthreads();
        // stage x tile (rows lr + 32c), XOR-swizzled k4 slot per 8-row group
        #pragma unroll
        for (int c = 0; c < 4; ++c) {
            const int row = lr + (c << 5);
            const float4 v = *(const float4*)(xbase + (size_t)row * D_ + k0 + lk);
            const int swz = ((lk4 ^ (row >> 3)) & 7) << 2;
            *(float4*)(xs + row * 36 + swz) = v;
        }
        // stage Ws1 tile (a = lr + 32c), linear
        #pragma unroll
        for (int c = 0; c < 8; ++c) {
            const int a = lr + (c << 5);
            const float4 v = *(const float4*)(Ws1 + (size_t)a * D_ + k0 + lk);
            *(float4*)(wsm + a * 36 + lk) = v;
        }
        __syncthreads();
        #pragma unroll
        for (int k4 = 0; k4 < 8; ++k4) {
            float4 xv[8];
            #pragma unroll
            for (int i = 0; i < 8; ++i)
                xv[i] = *(const float4*)(xs + (ty * 8 + i) * 36 + (((k4 ^ ty) & 7) << 2));
            #pragma unroll
            for (int j = 0; j < 16; ++j) {
                const float4 wv = *(const float4*)(wsm + (tx + (j << 4)) * 36 + (k4 << 2));
                #pragma unroll
                for (int i = 0; i < 8; ++i) {
                    acc[i][j] = fmaf(xv[i].x, wv.x, acc[i][j]);
                    acc[i][j] = fmaf(xv[i].y, wv.y, acc[i][j]);
                    acc[i][j] = fmaf(xv[i].z, wv.z, acc[i][j]);
                    acc[i][j] = fmaf(xv[i].w, wv.w, acc[i][j]);
                }
            }
        }
    }

    // tanh in-register
    #pragma unroll
    for (int i = 0; i < 8; ++i)
        #pragma unroll
        for (int j = 0; j < 16; ++j) acc[i][j] = tanhf(acc[i][j]);

    // fused Ws2 projection: score(s,r) = sum_a Ws2[r,a]*d1[s,a]
    // a-dim is split: 16 cols in-register (j), 16 lanes (tx) via shuffle reduce
    #pragma unroll
    for (int r = 0; r < R_; ++r) {
        float w2v[16];
        #pragma unroll
        for (int j = 0; j < 16; ++j) w2v[j] = Ws2[r * DA_ + tx + (j << 4)];
        float p[8];
        #pragma unroll
        for (int i = 0; i < 8; ++i) {
            float s = 0.f;
            #pragma unroll
            for (int j = 0; j < 16; ++j) s = fmaf(w2v[j], acc[i][j], s);
            p[i] = s;
        }
        #pragma unroll
        for (int off = 1; off < 16; off <<= 1)
            #pragma unroll
            for (int i = 0; i < 8; ++i) p[i] += __shfl_xor(p[i], off);
        if (tx == r) {
            #pragma unroll
            for (int i = 0; i < 8; ++i)
                scores[((size_t)b * R_ + r) * S_ + s0 + ty * 8 + i] = p[i];
        }
    }
}

// ---------------------------------------------------------------------------
// k2: softmax over s (length 4096) for each of B*R = 256 rows. One block/row.
// ---------------------------------------------------------------------------
__global__ __launch_bounds__(256) void k2_softmax(float* __restrict__ sc)
{
    const int row = blockIdx.x;
    float* p = sc + (size_t)row * S_;
    const int tid = threadIdx.x;
    const int wave = tid >> 6, lane = tid & 63;

    float v[16];
    float m = -1e30f;
    #pragma unroll
    for (int i = 0; i < 16; ++i) {
        v[i] = p[tid + (i << 8)];
        m = fmaxf(m, v[i]);
    }
    #pragma unroll
    for (int off = 32; off >= 1; off >>= 1) m = fmaxf(m, __shfl_xor(m, off));
    __shared__ float rmax[4], rsum[4];
    if (lane == 0) rmax[wave] = m;
    __syncthreads();
    m = fmaxf(fmaxf(rmax[0], rmax[1]), fmaxf(rmax[2], rmax[3]));

    float s = 0.f;
    #pragma unroll
    for (int i = 0; i < 16; ++i) {
        v[i] = expf(v[i] - m);
        s += v[i];
    }
    #pragma unroll
    for (int off = 32; off >= 1; off >>= 1) s += __shfl_xor(s, off);
    if (lane == 0) rsum[wave] = s;
    __syncthreads();
    s = rsum[0] + rsum[1] + rsum[2] + rsum[3];
    const float inv = 1.f / s;
    #pragma unroll
    for (int i = 0; i < 16; ++i) p[tid + (i << 8)] = v[i] * inv;
}

// ---------------------------------------------------------------------------
// k3: outputs[b,r,d] = sum_s A[b,r,s] * x[b,s,d]. Memory-bound re-read of x.
// grid = B * 16 s-chunks (chunk=256); block 256, each thread owns 2 d's.
// Partial sums accumulated with atomicAdd into zero-initialized d_out.
// ---------------------------------------------------------------------------
#define SC3 256
__global__ __launch_bounds__(256) void k3_outputs(
    const float* __restrict__ A, const float* __restrict__ x,
    float* __restrict__ out)
{
    const int blk = blockIdx.x;
    const int b  = blk >> 4;
    const int s0 = (blk & 15) * SC3;
    const int tid = threadIdx.x;

    __shared__ float As[R_ * SC3];
    for (int i = tid; i < R_ * SC3; i += 256) {
        const int r = i >> 8, sl = i & (SC3 - 1);
        As[i] = A[((size_t)b * R_ + r) * S_ + s0 + sl];
    }
    __syncthreads();

    float acc[R_][2];
    #pragma unroll
    for (int r = 0; r < R_; ++r) { acc[r][0] = 0.f; acc[r][1] = 0.f; }

    const float* xp = x + ((size_t)b * S_ + s0) * D_ + tid * 2;
    for (int sl = 0; sl < SC3; ++sl) {
        const float2 xv = *(const float2*)(xp + (size_t)sl * D_);
        #pragma unroll
        for (int r = 0; r < R_; ++r) {
            const float a = As[r * SC3 + sl];   // LDS broadcast (free)
            acc[r][0] = fmaf(a, xv.x, acc[r][0]);
            acc[r][1] = fmaf(a, xv.y, acc[r][1]);
        }
    }
    #pragma unroll
    for (int r = 0; r < R_; ++r) {
        float* o = &out[((size_t)b * R_ + r) * D_ + tid * 2];
        atomicAdd(o,     acc[r][0]);
        atomicAdd(o + 1, acc[r][1]);
    }
}

// ---------------------------------------------------------------------------
// k4: penalty += ||A_b A_b^T - I||_F^2 / B  (one block per batch)
// ---------------------------------------------------------------------------
__global__ __launch_bounds__(256) void k4_penalty(
    const float* __restrict__ A, float* __restrict__ pen)
{
    const int b = blockIdx.x;
    const int tid = threadIdx.x;
    __shared__ float As[R_ * 512];
    __shared__ float red[256];

    const int p  = tid & 63;        // pair index: r = p>>3, q = p&7
    const int g  = tid >> 6;        // s-quarter within chunk
    const int r  = p >> 3, q = p & 7;
    float accg = 0.f;

    for (int c = 0; c < 8; ++c) {
        if (c) __syncthreads();
        for (int i = tid; i < R_ * 512; i += 256) {
            const int rr = i >> 9, sl = i & 511;
            As[i] = A[((size_t)b * R_ + rr) * S_ + c * 512 + sl];
        }
        __syncthreads();
        const int sb = g * 128;
        for (int sl = sb; sl < sb + 128; ++sl)
            accg = fmaf(As[r * 512 + sl], As[q * 512 + sl], accg);
    }
    red[tid] = accg;
    __syncthreads();
    if (tid < 64) {
        float gv = red[tid] + red[tid + 64] + red[tid + 128] + red[tid + 192];
        float diff = gv - ((r == q) ? 1.0f : 0.0f);
        float v = diff * diff;
        #pragma unroll
        for (int off = 32; off >= 1; off >>= 1) v += __shfl_xor(v, off);
        if (tid == 0) atomicAdd(pen, v * (1.0f / (float)B_));
    }
}

// ---------------------------------------------------------------------------
extern "C" void kernel_launch(void* const* d_in, const int* in_sizes, int n_in,
                              void* d_out, int out_size, void* d_ws, size_t ws_size,
                              hipStream_t stream)
{
    const float* x   = (const float*)d_in[0];   // [B,S,D]
    const float* Ws1 = (const float*)d_in[1];   // [DA,D]
    const float* Ws2 = (const float*)d_in[2];   // [R,DA]
    float* out    = (float*)d_out;              // [B,R,D] + penalty scalar
    float* scores = (float*)d_ws;               // [B,R,S] = 4 MB

    hipMemsetAsync(d_out, 0, (size_t)out_size * sizeof(float), stream);

    k1_scores<<<(B_ * S_) / 128, 256, 0, stream>>>(x, Ws1, Ws2, scores);
    k2_softmax<<<B_ * R_, 256, 0, stream>>>(scores);
    k3_outputs<<<B_ * 16, 256, 0, stream>>>(scores, x, out);
    k4_penalty<<<B_, 256, 0, stream>>>(scores, out + (size_t)B_ * R_ * D_);
}

// Round 3
// 515.518 us; speedup vs baseline: 1.6006x; 1.6006x over previous
//
#include <hip/hip_runtime.h>
#include <hip/hip_bf16.h>

#define B_  32
#define S_  4096
#define D_  512
#define DA_ 256
#define R_  8

typedef __attribute__((ext_vector_type(8)))  short s16x8;
typedef __attribute__((ext_vector_type(16))) float f32x16;
typedef __attribute__((ext_vector_type(4)))  float f32x4;

// ws layout (bytes):
//   scores [B][R][S] f32 : 0        .. 4194304
//   wcvtH  (swizzled)    : 4194304  .. 4456448   (16 kt x 16KB)
//   wcvtL  (swizzled)    : 4456448  .. 4718592
//   part   [512][8][512] : 4718592  .. 13107200
#define WS_WH 4194304
#define WS_WL 4456448
#define WS_PART 4718592

__device__ __forceinline__ ushort bf16bits(float f) {
    __hip_bfloat16 h = __float2bfloat16(f);
    return *(ushort*)&h;
}
__device__ __forceinline__ float bf16val(ushort u) {
    __hip_bfloat16 h = *(__hip_bfloat16*)&u;
    return __bfloat162float(h);
}

// ---------------------------------------------------------------------------
// k0: convert Ws1 [256][512] f32 -> bf16 hi/lo in k1's exact swizzled LDS
// byte order: block kt (16KB): phys = c*64 + s'*16, logical kslot = s'^(c&3).
// ---------------------------------------------------------------------------
__global__ __launch_bounds__(256) void k0_wcvt(
    const float* __restrict__ Ws1, ushort* __restrict__ wh, ushort* __restrict__ wl)
{
    const int id = blockIdx.x * 256 + threadIdx.x;   // 0..16383
    const int kt = id >> 10, c = (id >> 2) & 255, sp = id & 3;
    const int q = sp ^ (c & 3);
    const float* src = Ws1 + (size_t)c * D_ + kt * 32 + q * 8;
    float v[8];
    #pragma unroll
    for (int j = 0; j < 8; ++j) v[j] = src[j];
    uint hp[4], lp[4];
    #pragma unroll
    for (int j = 0; j < 4; ++j) {
        ushort h0 = bf16bits(v[2*j]),   h1 = bf16bits(v[2*j+1]);
        float  r0 = v[2*j]   - bf16val(h0);
        float  r1 = v[2*j+1] - bf16val(h1);
        ushort l0 = bf16bits(r0), l1 = bf16bits(r1);
        hp[j] = (uint)h0 | ((uint)h1 << 16);
        lp[j] = (uint)l0 | ((uint)l1 << 16);
    }
    const size_t o = (size_t)kt * 8192 + c * 32 + sp * 8;   // ushort index
    *(uint4*)(wh + o) = make_uint4(hp[0], hp[1], hp[2], hp[3]);
    *(uint4*)(wl + o) = make_uint4(lp[0], lp[1], lp[2], lp[3]);
}

// ---------------------------------------------------------------------------
// k1: scores[b,r,s] = sum_a Ws2[r,a] * tanh( sum_d x[b,s,d]*Ws1[a,d] )
// MFMA 32x32x16 bf16, 3-product hi/lo split. Block 256 thr (4 waves 2Mx2N),
// tile 128(M s-rows) x 256(N a), wave-tile 64x128, BK=32.
// LDS 48KB: Ah/Al [128][32] swz + Bh/Bl [256][32] swz; epilogue aliases
// d1[32][264] f32 + w2[8][264] f32.
// ---------------------------------------------------------------------------
__global__ __launch_bounds__(256, 2) void k1_scores(
    const float* __restrict__ x, const ushort* __restrict__ wh,
    const ushort* __restrict__ wl, const float* __restrict__ Ws2,
    float* __restrict__ scores)
{
    __shared__ char smem[49152];
    ushort* Ah = (ushort*)smem;             // 8KB
    ushort* Al = (ushort*)(smem + 8192);    // 8KB
    ushort* Bh = (ushort*)(smem + 16384);   // 16KB
    ushort* Bl = (ushort*)(smem + 32768);   // 16KB

    const int tid  = threadIdx.x;
    const int w    = tid >> 6, lane = tid & 63;
    const int c    = lane & 31, h = lane >> 5;
    const int wrow = w >> 1,  wcol = w & 1;
    const int b    = blockIdx.x >> 5;
    const int s0   = (blockIdx.x & 31) << 7;
    const float* xbase = x + ((size_t)b * S_ + s0) * D_;

    f32x16 acc[2][4];
    #pragma unroll
    for (int i = 0; i < 2; ++i)
        #pragma unroll
        for (int j = 0; j < 4; ++j) acc[i][j] = (f32x16)0.f;

    const int mlow = tid >> 2;   // 0..63
    const int q    = tid & 3;    // logical k-slot

    for (int kt = 0; kt < 16; ++kt) {
        const int k0 = kt * 32;
        __syncthreads();
        // ---- stage A (x tile 128x32) with on-the-fly hi/lo split ----
        #pragma unroll
        for (int rr = 0; rr < 2; ++rr) {
            const int m = mlow + rr * 64;
            const float* src = xbase + (size_t)m * D_ + k0 + q * 8;
            const f32x4 v0 = *(const f32x4*)src;
            const f32x4 v1 = *(const f32x4*)(src + 4);
            float v[8] = {v0.x, v0.y, v0.z, v0.w, v1.x, v1.y, v1.z, v1.w};
            uint hp[4], lp[4];
            #pragma unroll
            for (int j = 0; j < 4; ++j) {
                ushort h0 = bf16bits(v[2*j]),   h1 = bf16bits(v[2*j+1]);
                float  r0 = v[2*j]   - bf16val(h0);
                float  r1 = v[2*j+1] - bf16val(h1);
                hp[j] = (uint)h0 | ((uint)h1 << 16);
                lp[j] = (uint)bf16bits(r0) | ((uint)bf16bits(r1) << 16);
            }
            const int sp = q ^ (m & 3);
            *(uint4*)(Ah + m * 32 + sp * 8) = make_uint4(hp[0], hp[1], hp[2], hp[3]);
            *(uint4*)(Al + m * 32 + sp * 8) = make_uint4(lp[0], lp[1], lp[2], lp[3]);
        }
        // ---- stage B (pre-swizzled) via global_load_lds, 16KB hi + 16KB lo ----
        {
            const size_t gbase = (size_t)kt * 8192;   // ushort idx
            #pragma unroll
            for (int ch = 0; ch < 4; ++ch) {
                const int chunk = w * 4 + ch;          // 0..15 (1KB each)
                const ushort* g  = wh + gbase + chunk * 512 + lane * 8;
                const ushort* g2 = wl + gbase + chunk * 512 + lane * 8;
                __builtin_amdgcn_global_load_lds(
                    (const __attribute__((address_space(1))) void*)g,
                    (__attribute__((address_space(3))) void*)(Bh + chunk * 512), 16, 0, 0);
                __builtin_amdgcn_global_load_lds(
                    (const __attribute__((address_space(1))) void*)g2,
                    (__attribute__((address_space(3))) void*)(Bl + chunk * 512), 16, 0, 0);
            }
        }
        __syncthreads();
        // ---- compute: 48 MFMA ----
        s16x8 a_h[2][2], a_l[2][2];
        #pragma unroll
        for (int mf = 0; mf < 2; ++mf)
            #pragma unroll
            for (int t = 0; t < 2; ++t) {
                const int row = wrow * 64 + mf * 32 + c;
                const int sl  = ((2 * t + h) ^ (c & 3)) * 8;
                a_h[mf][t] = *(const s16x8*)(Ah + row * 32 + sl);
                a_l[mf][t] = *(const s16x8*)(Al + row * 32 + sl);
            }
        #pragma unroll
        for (int nf = 0; nf < 4; ++nf) {
            const int rowb = wcol * 128 + nf * 32 + c;
            s16x8 b_h[2], b_l[2];
            #pragma unroll
            for (int t = 0; t < 2; ++t) {
                const int sl = ((2 * t + h) ^ (c & 3)) * 8;
                b_h[t] = *(const s16x8*)(Bh + rowb * 32 + sl);
                b_l[t] = *(const s16x8*)(Bl + rowb * 32 + sl);
            }
            #pragma unroll
            for (int t = 0; t < 2; ++t) {
                #pragma unroll
                for (int mf = 0; mf < 2; ++mf) {
                    acc[mf][nf] = __builtin_amdgcn_mfma_f32_32x32x16_bf16(a_h[mf][t], b_h[t], acc[mf][nf], 0, 0, 0);
                    acc[mf][nf] = __builtin_amdgcn_mfma_f32_32x32x16_bf16(a_h[mf][t], b_l[t], acc[mf][nf], 0, 0, 0);
                    acc[mf][nf] = __builtin_amdgcn_mfma_f32_32x32x16_bf16(a_l[mf][t], b_h[t], acc[mf][nf], 0, 0, 0);
                }
            }
        }
    }

    // ---- epilogue: tanh -> d1 in LDS (32-row phases) -> Ws2 projection ----
    float* d1 = (float*)smem;               // [32][264]
    float* w2 = (float*)(smem + 33792);     // [8][264]
    __syncthreads();                        // LDS (Bh/Bl) reads all done
    for (int i = tid; i < 2048; i += 256)
        w2[(i >> 8) * 264 + (i & 255)] = Ws2[i];

    #pragma unroll
    for (int p = 0; p < 4; ++p) {
        __syncthreads();                    // prev phase readers done
        if (wrow == (p >> 1)) {
            const int mf = p & 1;
            #pragma unroll
            for (int nf = 0; nf < 4; ++nf)
                #pragma unroll
                for (int j = 0; j < 16; ++j) {
                    const int srow = (j & 3) + 8 * (j >> 2) + 4 * h;
                    const float v = acc[mf][nf][j];
                    const float e = __expf(2.f * v);
                    d1[srow * 264 + wcol * 128 + nf * 32 + c] = 1.f - 2.f / (e + 1.f);
                }
        }
        __syncthreads();
        const int sr = tid >> 3, r = tid & 7;
        float sum = 0.f;
        #pragma unroll 8
        for (int a4 = 0; a4 < 64; ++a4) {
            const f32x4 dv = *(const f32x4*)(d1 + sr * 264 + a4 * 4);
            const f32x4 wv = *(const f32x4*)(w2 + r  * 264 + a4 * 4);
            sum = fmaf(dv.x, wv.x, sum);
            sum = fmaf(dv.y, wv.y, sum);
            sum = fmaf(dv.z, wv.z, sum);
            sum = fmaf(dv.w, wv.w, sum);
        }
        scores[((size_t)b * R_ + r) * S_ + s0 + p * 32 + sr] = sum;
    }
}

// ---------------------------------------------------------------------------
// k2: softmax over s (4096) for each of B*R=256 rows
// ---------------------------------------------------------------------------
__global__ __launch_bounds__(256) void k2_softmax(float* __restrict__ sc)
{
    const int row = blockIdx.x;
    float* p = sc + (size_t)row * S_;
    const int tid = threadIdx.x;
    const int wave = tid >> 6, lane = tid & 63;

    float v[16];
    float m = -1e30f;
    #pragma unroll
    for (int i = 0; i < 16; ++i) { v[i] = p[tid + (i << 8)]; m = fmaxf(m, v[i]); }
    #pragma unroll
    for (int off = 32; off >= 1; off >>= 1) m = fmaxf(m, __shfl_xor(m, off));
    __shared__ float rmax[4], rsum[4];
    if (lane == 0) rmax[wave] = m;
    __syncthreads();
    m = fmaxf(fmaxf(rmax[0], rmax[1]), fmaxf(rmax[2], rmax[3]));
    float s = 0.f;
    #pragma unroll
    for (int i = 0; i < 16; ++i) { v[i] = __expf(v[i] - m); s += v[i]; }
    #pragma unroll
    for (int off = 32; off >= 1; off >>= 1) s += __shfl_xor(s, off);
    if (lane == 0) rsum[wave] = s;
    __syncthreads();
    s = rsum[0] + rsum[1] + rsum[2] + rsum[3];
    const float inv = 1.f / s;
    #pragma unroll
    for (int i = 0; i < 16; ++i) p[tid + (i << 8)] = v[i] * inv;
}

// ---------------------------------------------------------------------------
// k3: partial outputs per (b, s-chunk of 256): part[blk][r][d], no atomics.
// ---------------------------------------------------------------------------
__global__ __launch_bounds__(256) void k3_outputs(
    const float* __restrict__ A, const float* __restrict__ x,
    float* __restrict__ part)
{
    const int blk = blockIdx.x;              // b*16 + chunk
    const int b = blk >> 4, s0 = (blk & 15) << 8;
    const int tid = threadIdx.x;
    const int sg = tid >> 7, dq = (tid & 127) << 2;
    __shared__ float As[R_ * 256];
    __shared__ float red[R_ * 512];
    for (int i = tid; i < R_ * 256; i += 256)
        As[i] = A[((size_t)b * R_ + (i >> 8)) * S_ + s0 + (i & 255)];
    __syncthreads();
    float acc[R_][4];
    #pragma unroll
    for (int r = 0; r < R_; ++r)
        #pragma unroll
        for (int j = 0; j < 4; ++j) acc[r][j] = 0.f;
    const float* xp = x + ((size_t)b * S_ + s0) * D_ + dq;
    #pragma unroll 4
    for (int sl = sg; sl < 256; sl += 2) {
        const f32x4 xv = *(const f32x4*)(xp + (size_t)sl * D_);
        #pragma unroll
        for (int r = 0; r < R_; ++r) {
            const float a = As[r * 256 + sl];
            acc[r][0] = fmaf(a, xv.x, acc[r][0]);
            acc[r][1] = fmaf(a, xv.y, acc[r][1]);
            acc[r][2] = fmaf(a, xv.z, acc[r][2]);
            acc[r][3] = fmaf(a, xv.w, acc[r][3]);
        }
    }
    if (sg == 0) {
        #pragma unroll
        for (int r = 0; r < R_; ++r)
            *(f32x4*)(red + r * 512 + dq) = *(f32x4*)acc[r];
    }
    __syncthreads();
    if (sg == 1) {
        #pragma unroll
        for (int r = 0; r < R_; ++r) {
            f32x4 o = *(f32x4*)(red + r * 512 + dq);
            o.x += acc[r][0]; o.y += acc[r][1]; o.z += acc[r][2]; o.w += acc[r][3];
            *(f32x4*)(part + ((size_t)blk * R_ + r) * D_ + dq) = o;
        }
    }
}

__global__ __launch_bounds__(256) void k3b_reduce(
    const float* __restrict__ part, float* __restrict__ out)
{
    const int o = blockIdx.x * 256 + threadIdx.x;   // 0..131071
    const int b = o >> 12, rd = o & 4095;
    float s = 0.f;
    #pragma unroll
    for (int ch = 0; ch < 16; ++ch)
        s += part[((size_t)(b * 16 + ch)) * 4096 + rd];
    out[o] = s;
}

// ---------------------------------------------------------------------------
// k4: penalty += ||A_b A_b^T - I||_F^2 / B  (one block per batch)
// ---------------------------------------------------------------------------
__global__ __launch_bounds__(256) void k4_penalty(
    const float* __restrict__ A, float* __restrict__ pen)
{
    const int b = blockIdx.x;
    const int tid = threadIdx.x;
    __shared__ float As[R_ * 512];
    __shared__ float red[256];
    const int p = tid & 63;
    const int g = tid >> 6;
    const int r = p >> 3, qq = p & 7;
    float accg = 0.f;
    for (int cc = 0; cc < 8; ++cc) {
        if (cc) __syncthreads();
        for (int i = tid; i < R_ * 512; i += 256) {
            const int rr = i >> 9, sl = i & 511;
            As[i] = A[((size_t)b * R_ + rr) * S_ + cc * 512 + sl];
        }
        __syncthreads();
        const int sb = g * 128;
        for (int sl = sb; sl < sb + 128; ++sl)
            accg = fmaf(As[r * 512 + sl], As[qq * 512 + sl], accg);
    }
    red[tid] = accg;
    __syncthreads();
    if (tid < 64) {
        float gv = red[tid] + red[tid + 64] + red[tid + 128] + red[tid + 192];
        float diff = gv - ((r == qq) ? 1.0f : 0.0f);
        float v = diff * diff;
        #pragma unroll
        for (int off = 32; off >= 1; off >>= 1) v += __shfl_xor(v, off);
        if (tid == 0) atomicAdd(pen, v * (1.0f / (float)B_));
    }
}

// ---------------------------------------------------------------------------
extern "C" void kernel_launch(void* const* d_in, const int* in_sizes, int n_in,
                              void* d_out, int out_size, void* d_ws, size_t ws_size,
                              hipStream_t stream)
{
    const float* x   = (const float*)d_in[0];
    const float* Ws1 = (const float*)d_in[1];
    const float* Ws2 = (const float*)d_in[2];
    float* out = (float*)d_out;

    char* ws = (char*)d_ws;
    float*  scores = (float*)ws;
    ushort* wh     = (ushort*)(ws + WS_WH);
    ushort* wl     = (ushort*)(ws + WS_WL);
    float*  part   = (float*)(ws + WS_PART);

    hipMemsetAsync(d_out, 0, (size_t)out_size * sizeof(float), stream);

    k0_wcvt   <<<64,   256, 0, stream>>>(Ws1, wh, wl);
    k1_scores <<<1024, 256, 0, stream>>>(x, wh, wl, Ws2, scores);
    k2_softmax<<<256,  256, 0, stream>>>(scores);
    k3_outputs<<<512,  256, 0, stream>>>(scores, x, part);
    k3b_reduce<<<512,  256, 0, stream>>>(part, out);
    k4_penalty<<<32,   256, 0, stream>>>(scores, out + (size_t)B_ * R_ * D_);
}